// Round 1
// baseline (1830.366 us; speedup 1.0000x reference)
//
#include <hip/hip_runtime.h>

typedef _Float16 v8h __attribute__((ext_vector_type(8)));
typedef _Float16 v4h __attribute__((ext_vector_type(4)));
typedef float    v4f __attribute__((ext_vector_type(4)));

#define GK 6432      // K of the big GEMM (= flatten size F)
#define GN 6432      // N of the big GEMM
#define GM 2048      // batch
#define GNPAD 6528   // N padded to 51*128 for safe staging

// ---------------------------------------------------------------------------
// Weight conversion: wl fp32 [6432,6432] -> fp16 [6528,6432], pad rows zeroed
// ---------------------------------------------------------------------------
__global__ void convert_w(const float* __restrict__ wl, _Float16* __restrict__ Wh)
{
    const int row = blockIdx.y;
    const int col = (blockIdx.x * 256 + threadIdx.x) * 4;
    if (col >= GK) return;
    v4h h;
    if (row < GN) {
        const float4 f = *(const float4*)(wl + (long)row * GK + col);
        h[0] = (_Float16)f.x; h[1] = (_Float16)f.y;
        h[2] = (_Float16)f.z; h[3] = (_Float16)f.w;
    } else {
        h[0] = (_Float16)0.f; h[1] = (_Float16)0.f;
        h[2] = (_Float16)0.f; h[3] = (_Float16)0.f;
    }
    *(v4h*)(Wh + (long)row * GK + col) = h;
}

// ---------------------------------------------------------------------------
// Multi-scale conv feature extractor. One block per batch item.
// Produces F0 [2048, 6432] fp16, layout b*6432 + c2*201 + v  (v concatenates
// scale outputs 117|57|27).
// ---------------------------------------------------------------------------
// LDS layout (floats):
#define SX   0       // [4][512]  x (480 valid)
#define SX2  2048    // [4][272]  coarse s=2 (240 valid)
#define SX4  3136    // [4][144]  coarse s=4 (120 valid)
#define SW1  3712    // [16*4*5]
#define SB1  4032    // [16]
#define SW2  4048    // [32*16*5]
#define SB2  6608    // [32]
#define SP1  6640    // [16][448] pooled conv1, concat 238|118|58 at 0/238/356
#define LDSZ 13808

__global__ __launch_bounds__(256) void conv_feat(
    const float* __restrict__ x,
    const float* __restrict__ w1, const float* __restrict__ b1,
    const float* __restrict__ w2, const float* __restrict__ b2,
    _Float16* __restrict__ F0)
{
    __shared__ float lds[LDSZ];
    const int tid = threadIdx.x;
    const long b  = blockIdx.x;

    // ---- stage x and weights ----
    for (int i = tid; i < 1920; i += 256) {
        int c = i / 480, t = i % 480;
        lds[SX + c * 512 + t] = x[(b * 4 + c) * 480 + t];
    }
    for (int i = tid; i < 320;  i += 256) lds[SW1 + i] = w1[i];
    for (int i = tid; i < 16;   i += 256) lds[SB1 + i] = b1[i];
    for (int i = tid; i < 2560; i += 256) lds[SW2 + i] = w2[i];
    for (int i = tid; i < 32;   i += 256) lds[SB2 + i] = b2[i];
    __syncthreads();

    // ---- coarse grain ----
    for (int i = tid; i < 960; i += 256) {
        int c = i / 240, t = i % 240;
        lds[SX2 + c * 272 + t] = 0.5f * (lds[SX + c * 512 + 2 * t] + lds[SX + c * 512 + 2 * t + 1]);
    }
    for (int i = tid; i < 480; i += 256) {
        int c = i / 120, t = i % 120;
        float s = lds[SX + c * 512 + 4 * t]     + lds[SX + c * 512 + 4 * t + 1]
                + lds[SX + c * 512 + 4 * t + 2] + lds[SX + c * 512 + 4 * t + 3];
        lds[SX4 + c * 144 + t] = 0.25f * s;
    }
    __syncthreads();

    // ---- conv1 + relu + maxpool2 -> sp1 ----
    // jobs: c1 (16) x 34 runs of NU=13 pooled outputs (19 runs s1, 10 s2, 5 s4)
    for (int jid = tid; jid < 16 * 34; jid += 256) {
        const int c1 = jid / 34, rid = jid % 34;
        const int sidx = (rid < 19) ? 0 : (rid < 29 ? 1 : 2);
        const int r0   = (sidx == 0) ? rid : (sidx == 1 ? rid - 19 : rid - 29);
        const int u0   = r0 * 13;
        const int xbase  = (sidx == 0) ? SX  : (sidx == 1 ? SX2 : SX4);
        const int xpitch = (sidx == 0) ? 512 : (sidx == 1 ? 272 : 144);
        const int P      = (sidx == 0) ? 238 : (sidx == 1 ? 118 : 58);
        const int pofs   = (sidx == 0) ? 0   : (sidx == 1 ? 238 : 356);

        float acc[26];
        const float bias = lds[SB1 + c1];
        #pragma unroll
        for (int i = 0; i < 26; ++i) acc[i] = bias;

        #pragma unroll
        for (int ci = 0; ci < 4; ++ci) {
            float w[30];
            const float* xr = &lds[xbase + ci * xpitch + 2 * u0];
            #pragma unroll
            for (int q = 0; q < 15; ++q) {
                float2 t2 = *(const float2*)(xr + 2 * q);
                w[2 * q] = t2.x; w[2 * q + 1] = t2.y;
            }
            float wt[5];
            #pragma unroll
            for (int k = 0; k < 5; ++k) wt[k] = lds[SW1 + (c1 * 4 + ci) * 5 + k];
            #pragma unroll
            for (int i = 0; i < 26; ++i) {
                #pragma unroll
                for (int k = 0; k < 5; ++k) acc[i] += w[i + k] * wt[k];
            }
        }
        #pragma unroll
        for (int i = 0; i < 13; ++i) {
            int u = u0 + i;
            if (u < P)
                lds[SP1 + c1 * 448 + pofs + u] = fmaxf(fmaxf(acc[2 * i], acc[2 * i + 1]), 0.f);
        }
    }
    __syncthreads();

    // ---- conv2 + relu + maxpool2 -> F0 ----
    // jobs: c2 (32) x 17 runs of NV=13 outputs (9 runs s1, 5 s2, 3 s4)
    for (int jid = tid; jid < 32 * 17; jid += 256) {
        const int c2 = jid / 17, rid = jid % 17;
        const int sidx = (rid < 9) ? 0 : (rid < 14 ? 1 : 2);
        const int r0   = (sidx == 0) ? rid : (sidx == 1 ? rid - 9 : rid - 14);
        const int v0   = r0 * 13;
        const int pbase = (sidx == 0) ? 0   : (sidx == 1 ? 238 : 356);
        const int Pv    = (sidx == 0) ? 117 : (sidx == 1 ? 57  : 27);
        const int vout  = (sidx == 0) ? 0   : (sidx == 1 ? 117 : 174);

        float acc[26];
        const float bias = lds[SB2 + c2];
        #pragma unroll
        for (int i = 0; i < 26; ++i) acc[i] = bias;

        for (int c1 = 0; c1 < 16; ++c1) {
            float w[30];
            const float* pr = &lds[SP1 + c1 * 448 + pbase + 2 * v0];
            #pragma unroll
            for (int q = 0; q < 15; ++q) {
                float2 t2 = *(const float2*)(pr + 2 * q);
                w[2 * q] = t2.x; w[2 * q + 1] = t2.y;
            }
            float wt[5];
            #pragma unroll
            for (int k = 0; k < 5; ++k) wt[k] = lds[SW2 + (c2 * 16 + c1) * 5 + k];
            #pragma unroll
            for (int i = 0; i < 26; ++i) {
                #pragma unroll
                for (int k = 0; k < 5; ++k) acc[i] += w[i + k] * wt[k];
            }
        }
        #pragma unroll
        for (int i = 0; i < 13; ++i) {
            int v = v0 + i;
            if (v < Pv) {
                float f = fmaxf(fmaxf(acc[2 * i], acc[2 * i + 1]), 0.f);
                F0[b * GK + c2 * 201 + vout + v] = (_Float16)f;
            }
        }
    }
}

// ---------------------------------------------------------------------------
// m97-style NT GEMM: C = relu(A @ Bw^T + bias), A [2048,6432] fp16,
// Bw [6528(pad),6432] fp16, C [2048,6432] fp16. 128x128 tile, BK=32,
// 4 waves x (4x4) mfma_f32_16x16x32_f16.
// ---------------------------------------------------------------------------
__global__ __launch_bounds__(256) void gemm_relu(
    const _Float16* __restrict__ A, const _Float16* __restrict__ Bw,
    const float* __restrict__ bias, _Float16* __restrict__ C)
{
    __shared__ _Float16 sA[128 * 32];
    __shared__ _Float16 sB[128 * 32];
    const int tid  = threadIdx.x;
    const int lane = tid & 63;
    const int wave = tid >> 6;
    const int wm = wave & 1, wn = wave >> 1;
    const long tile_m = (long)blockIdx.y * 128;
    const long tile_n = (long)blockIdx.x * 128;

    // staging: wave covers rows [32*wave, 32*wave+32) of each tile, 2 insts
    const int srow = (wave << 5) + (lane >> 2);
    const int scol = (lane & 3) << 3;                 // fp16 elems
    const _Float16* gA = A  + (tile_m + srow) * (long)GK + scol;
    const _Float16* gB = Bw + (tile_n + srow) * (long)GK + scol;
    _Float16* lA0 = &sA[(wave << 5) * 32];
    _Float16* lA1 = &sA[(wave << 5) * 32 + 16 * 32];
    _Float16* lB0 = &sB[(wave << 5) * 32];
    _Float16* lB1 = &sB[(wave << 5) * 32 + 16 * 32];

    const int fr = lane & 15;
    const int fk = (lane >> 4) << 3;
    int aoff[4], boff[4];
    #pragma unroll
    for (int i = 0; i < 4; ++i) {
        aoff[i] = ((wm << 6) + (i << 4) + fr) * 32 + fk;
        boff[i] = ((wn << 6) + (i << 4) + fr) * 32 + fk;
    }

    v4f acc[4][4];
    #pragma unroll
    for (int i = 0; i < 4; ++i) {
        #pragma unroll
        for (int j = 0; j < 4; ++j) { v4f z = {0.f, 0.f, 0.f, 0.f}; acc[i][j] = z; }
    }

    for (int k0 = 0; k0 < GK; k0 += 32) {
        __builtin_amdgcn_global_load_lds(
            (const __attribute__((address_space(1))) void*)(gA + k0),
            (__attribute__((address_space(3))) void*)lA0, 16, 0, 0);
        __builtin_amdgcn_global_load_lds(
            (const __attribute__((address_space(1))) void*)(gA + 16 * (long)GK + k0),
            (__attribute__((address_space(3))) void*)lA1, 16, 0, 0);
        __builtin_amdgcn_global_load_lds(
            (const __attribute__((address_space(1))) void*)(gB + k0),
            (__attribute__((address_space(3))) void*)lB0, 16, 0, 0);
        __builtin_amdgcn_global_load_lds(
            (const __attribute__((address_space(1))) void*)(gB + 16 * (long)GK + k0),
            (__attribute__((address_space(3))) void*)lB1, 16, 0, 0);
        __syncthreads();

        v8h af[4], bf[4];
        #pragma unroll
        for (int i = 0; i < 4; ++i) {
            af[i] = *(const v8h*)&sA[aoff[i]];
            bf[i] = *(const v8h*)&sB[boff[i]];
        }
        #pragma unroll
        for (int i = 0; i < 4; ++i) {
            #pragma unroll
            for (int j = 0; j < 4; ++j)
                acc[i][j] = __builtin_amdgcn_mfma_f32_16x16x32_f16(af[i], bf[j], acc[i][j], 0, 0, 0);
        }
        __syncthreads();
    }

    // epilogue: C/D layout col=lane&15, row=(lane>>4)*4+reg (m89-verified)
    #pragma unroll
    for (int j = 0; j < 4; ++j) {
        const long col = tile_n + (wn << 6) + (j << 4) + fr;
        if (col < GN) {
            const float bv = bias[col];
            #pragma unroll
            for (int i = 0; i < 4; ++i) {
                const long row = tile_m + (wm << 6) + (i << 4) + ((lane >> 4) << 2);
                #pragma unroll
                for (int r = 0; r < 4; ++r) {
                    float v = acc[i][j][r] + bv;
                    v = v > 0.f ? v : 0.f;
                    C[(row + r) * (long)GN + col] = (_Float16)v;
                }
            }
        }
    }
}

// ---------------------------------------------------------------------------
// Final projection: out[b,o] = sum_k F[b,k]*wo[o,k] + bo[o].  One wave/row.
// ---------------------------------------------------------------------------
__global__ __launch_bounds__(64) void final_out(
    const _Float16* __restrict__ F, const float* __restrict__ wo,
    const float* __restrict__ bo, float* __restrict__ out)
{
    const long b   = blockIdx.x;
    const int lane = threadIdx.x;
    float acc[5] = {0.f, 0.f, 0.f, 0.f, 0.f};
    const _Float16* f = F + b * GK;
    for (int k = lane; k < GK; k += 64) {
        const float fv = (float)f[k];
        #pragma unroll
        for (int o = 0; o < 5; ++o) acc[o] += fv * wo[o * GK + k];
    }
    #pragma unroll
    for (int o = 0; o < 5; ++o) {
        #pragma unroll
        for (int off = 32; off > 0; off >>= 1) acc[o] += __shfl_down(acc[o], off, 64);
    }
    if (lane == 0) {
        #pragma unroll
        for (int o = 0; o < 5; ++o) out[b * 5 + o] = acc[o] + bo[o];
    }
}

// ---------------------------------------------------------------------------
extern "C" void kernel_launch(void* const* d_in, const int* in_sizes, int n_in,
                              void* d_out, int out_size, void* d_ws, size_t ws_size,
                              hipStream_t stream)
{
    const float* x  = (const float*)d_in[0];
    const float* w1 = (const float*)d_in[1];
    const float* b1 = (const float*)d_in[2];
    const float* w2 = (const float*)d_in[3];
    const float* b2 = (const float*)d_in[4];
    const float* wl = (const float*)d_in[5];
    const float* bl = (const float*)d_in[6];
    const float* wo = (const float*)d_in[7];
    const float* bo = (const float*)d_in[8];
    float* out = (float*)d_out;

    char* ws = (char*)d_ws;
    _Float16* Wh = (_Float16*)ws;                                   // 6528*6432*2 = 83,976,192 B
    _Float16* F0 = (_Float16*)(ws + 83976192);                      // 2048*6432*2 = 26,345,472 B
    _Float16* F1 = (_Float16*)(ws + 83976192 + 26345472);           // total ~137 MB

    convert_w<<<dim3(7, GNPAD), 256, 0, stream>>>(wl, Wh);
    conv_feat<<<GM, 256, 0, stream>>>(x, w1, b1, w2, b2, F0);
    dim3 g(51, 16);
    gemm_relu<<<g, 256, 0, stream>>>(F0, Wh, bl, F1);
    gemm_relu<<<g, 256, 0, stream>>>(F1, Wh, bl, F0);
    gemm_relu<<<g, 256, 0, stream>>>(F0, Wh, bl, F1);
    gemm_relu<<<g, 256, 0, stream>>>(F1, Wh, bl, F0);
    final_out<<<GM, 64, 0, stream>>>(F0, wo, bo, out);
}

// Round 3
// 1725.869 us; speedup vs baseline: 1.0605x; 1.0605x over previous
//
#include <hip/hip_runtime.h>

typedef _Float16 v8h __attribute__((ext_vector_type(8)));
typedef _Float16 v4h __attribute__((ext_vector_type(4)));
typedef float    v4f __attribute__((ext_vector_type(4)));

#define GK 6432      // K of the big GEMM (= flatten size F)
#define GN 6432      // N of the big GEMM
#define GM 2048      // batch
#define GNPAD 6528   // N padded to 51*128 for safe staging

// ---------------------------------------------------------------------------
// Weight conversion: wl fp32 [6432,6432] -> fp16 [6528,6432], pad rows zeroed
// ---------------------------------------------------------------------------
__global__ void convert_w(const float* __restrict__ wl, _Float16* __restrict__ Wh)
{
    const int row = blockIdx.y;
    const int col = (blockIdx.x * 256 + threadIdx.x) * 4;
    if (col >= GK) return;
    v4h h;
    if (row < GN) {
        const float4 f = *(const float4*)(wl + (long)row * GK + col);
        h[0] = (_Float16)f.x; h[1] = (_Float16)f.y;
        h[2] = (_Float16)f.z; h[3] = (_Float16)f.w;
    } else {
        h[0] = (_Float16)0.f; h[1] = (_Float16)0.f;
        h[2] = (_Float16)0.f; h[3] = (_Float16)0.f;
    }
    *(v4h*)(Wh + (long)row * GK + col) = h;
}

// ---------------------------------------------------------------------------
// Multi-scale conv feature extractor. One block per batch item.
// Produces F0 [2048, 6432] fp16, layout b*6432 + c2*201 + v.
// ---------------------------------------------------------------------------
#define SX   0
#define SX2  2048
#define SX4  3136
#define SW1  3712
#define SB1  4032
#define SW2  4048
#define SB2  6608
#define SP1  6640
#define LDSZ 13808

__global__ __launch_bounds__(256) void conv_feat(
    const float* __restrict__ x,
    const float* __restrict__ w1, const float* __restrict__ b1,
    const float* __restrict__ w2, const float* __restrict__ b2,
    _Float16* __restrict__ F0)
{
    __shared__ float lds[LDSZ];
    const int tid = threadIdx.x;
    const long b  = blockIdx.x;

    for (int i = tid; i < 1920; i += 256) {
        int c = i / 480, t = i % 480;
        lds[SX + c * 512 + t] = x[(b * 4 + c) * 480 + t];
    }
    for (int i = tid; i < 320;  i += 256) lds[SW1 + i] = w1[i];
    for (int i = tid; i < 16;   i += 256) lds[SB1 + i] = b1[i];
    for (int i = tid; i < 2560; i += 256) lds[SW2 + i] = w2[i];
    for (int i = tid; i < 32;   i += 256) lds[SB2 + i] = b2[i];
    __syncthreads();

    for (int i = tid; i < 960; i += 256) {
        int c = i / 240, t = i % 240;
        lds[SX2 + c * 272 + t] = 0.5f * (lds[SX + c * 512 + 2 * t] + lds[SX + c * 512 + 2 * t + 1]);
    }
    for (int i = tid; i < 480; i += 256) {
        int c = i / 120, t = i % 120;
        float s = lds[SX + c * 512 + 4 * t]     + lds[SX + c * 512 + 4 * t + 1]
                + lds[SX + c * 512 + 4 * t + 2] + lds[SX + c * 512 + 4 * t + 3];
        lds[SX4 + c * 144 + t] = 0.25f * s;
    }
    __syncthreads();

    for (int jid = tid; jid < 16 * 34; jid += 256) {
        const int c1 = jid / 34, rid = jid % 34;
        const int sidx = (rid < 19) ? 0 : (rid < 29 ? 1 : 2);
        const int r0   = (sidx == 0) ? rid : (sidx == 1 ? rid - 19 : rid - 29);
        const int u0   = r0 * 13;
        const int xbase  = (sidx == 0) ? SX  : (sidx == 1 ? SX2 : SX4);
        const int xpitch = (sidx == 0) ? 512 : (sidx == 1 ? 272 : 144);
        const int P      = (sidx == 0) ? 238 : (sidx == 1 ? 118 : 58);
        const int pofs   = (sidx == 0) ? 0   : (sidx == 1 ? 238 : 356);

        float acc[26];
        const float bias = lds[SB1 + c1];
        #pragma unroll
        for (int i = 0; i < 26; ++i) acc[i] = bias;

        #pragma unroll
        for (int ci = 0; ci < 4; ++ci) {
            float w[30];
            const float* xr = &lds[xbase + ci * xpitch + 2 * u0];
            #pragma unroll
            for (int q = 0; q < 15; ++q) {
                float2 t2 = *(const float2*)(xr + 2 * q);
                w[2 * q] = t2.x; w[2 * q + 1] = t2.y;
            }
            float wt[5];
            #pragma unroll
            for (int k = 0; k < 5; ++k) wt[k] = lds[SW1 + (c1 * 4 + ci) * 5 + k];
            #pragma unroll
            for (int i = 0; i < 26; ++i) {
                #pragma unroll
                for (int k = 0; k < 5; ++k) acc[i] += w[i + k] * wt[k];
            }
        }
        #pragma unroll
        for (int i = 0; i < 13; ++i) {
            int u = u0 + i;
            if (u < P)
                lds[SP1 + c1 * 448 + pofs + u] = fmaxf(fmaxf(acc[2 * i], acc[2 * i + 1]), 0.f);
        }
    }
    __syncthreads();

    for (int jid = tid; jid < 32 * 17; jid += 256) {
        const int c2 = jid / 17, rid = jid % 17;
        const int sidx = (rid < 9) ? 0 : (rid < 14 ? 1 : 2);
        const int r0   = (sidx == 0) ? rid : (sidx == 1 ? rid - 9 : rid - 14);
        const int v0   = r0 * 13;
        const int pbase = (sidx == 0) ? 0   : (sidx == 1 ? 238 : 356);
        const int Pv    = (sidx == 0) ? 117 : (sidx == 1 ? 57  : 27);
        const int vout  = (sidx == 0) ? 0   : (sidx == 1 ? 117 : 174);

        float acc[26];
        const float bias = lds[SB2 + c2];
        #pragma unroll
        for (int i = 0; i < 26; ++i) acc[i] = bias;

        for (int c1 = 0; c1 < 16; ++c1) {
            float w[30];
            const float* pr = &lds[SP1 + c1 * 448 + pbase + 2 * v0];
            #pragma unroll
            for (int q = 0; q < 15; ++q) {
                float2 t2 = *(const float2*)(pr + 2 * q);
                w[2 * q] = t2.x; w[2 * q + 1] = t2.y;
            }
            float wt[5];
            #pragma unroll
            for (int k = 0; k < 5; ++k) wt[k] = lds[SW2 + (c2 * 16 + c1) * 5 + k];
            #pragma unroll
            for (int i = 0; i < 26; ++i) {
                #pragma unroll
                for (int k = 0; k < 5; ++k) acc[i] += w[i + k] * wt[k];
            }
        }
        #pragma unroll
        for (int i = 0; i < 13; ++i) {
            int v = v0 + i;
            if (v < Pv) {
                float f = fmaxf(fmaxf(acc[2 * i], acc[2 * i + 1]), 0.f);
                F0[b * GK + c2 * 201 + vout + v] = (_Float16)f;
            }
        }
    }
}

// ---------------------------------------------------------------------------
// NT GEMM: C = relu(A @ Bw^T + bias). 128x128 tile, BK=32, double-buffered
// LDS (single barrier/iter), XOR-swizzled LDS layout (conflict-free b128
// reads), XCD-aware block swizzle. fp32 MFMA accumulation.
// ---------------------------------------------------------------------------
__global__ __launch_bounds__(256) void gemm_relu(
    const _Float16* __restrict__ A, const _Float16* __restrict__ Bw,
    const float* __restrict__ bias, _Float16* __restrict__ C)
{
    __shared__ _Float16 sA[2][128 * 32];
    __shared__ _Float16 sB[2][128 * 32];
    const int tid  = threadIdx.x;
    const int lane = tid & 63;
    const int wave = tid >> 6;
    const int wm = wave & 1, wn = wave >> 1;

    // XCD swizzle: within a group of 128 ids, XCD (id&7) gets ONE n-tile and
    // all 16 m-tiles -> its 1.6MB B-strip stays L2-resident.
    const int id = blockIdx.x;          // 0..815
    int n_t, m_t;
    if (id < 768) {
        n_t = ((id >> 7) << 3) | (id & 7);
        m_t = (id >> 3) & 15;
    } else {
        const int r = id - 768;
        n_t = 48 + r % 3;
        m_t = r / 3;
    }
    const long tile_m = (long)m_t * 128;
    const long tile_n = (long)n_t * 128;

    // staging: lane l covers LDS chunk (row = base+l/4, slot = l&3).
    // XOR swizzle: slot q at row r holds global k-phase q ^ s(r),
    // s(r) = (r&3) ^ ((r>>2)&3).
    const int lr   = lane >> 2;
    const int sfn  = (lr & 3) ^ ((lr >> 2) & 3);
    const int scol = (((lane & 3) ^ sfn) << 3);       // fp16 elems
    const int srow = (wave << 5) + lr;
    const _Float16* gA = A  + (tile_m + srow) * (long)GK + scol;
    const _Float16* gB = Bw + (tile_n + srow) * (long)GK + scol;
    const int ldsbase = (wave << 5) * 32;

    // fragment read offsets (swizzled slot)
    const int fr = lane & 15;
    const int fp = lane >> 4;                          // k-phase 0..3
    const int fslot = fp ^ ((fr & 3) ^ ((fr >> 2) & 3));
    int aoff[4], boff[4];
    #pragma unroll
    for (int i = 0; i < 4; ++i) {
        aoff[i] = ((wm << 6) + (i << 4) + fr) * 32 + (fslot << 3);
        boff[i] = ((wn << 6) + (i << 4) + fr) * 32 + (fslot << 3);
    }

    v4f acc[4][4];
    #pragma unroll
    for (int i = 0; i < 4; ++i) {
        #pragma unroll
        for (int j = 0; j < 4; ++j) { v4f z = {0.f, 0.f, 0.f, 0.f}; acc[i][j] = z; }
    }

    auto stage = [&](int k0, int buf) {
        _Float16* dA = &sA[buf][ldsbase];
        _Float16* dB = &sB[buf][ldsbase];
        __builtin_amdgcn_global_load_lds(
            (const __attribute__((address_space(1))) void*)(gA + k0),
            (__attribute__((address_space(3))) void*)dA, 16, 0, 0);
        __builtin_amdgcn_global_load_lds(
            (const __attribute__((address_space(1))) void*)(gA + 16 * (long)GK + k0),
            (__attribute__((address_space(3))) void*)(dA + 16 * 32), 16, 0, 0);
        __builtin_amdgcn_global_load_lds(
            (const __attribute__((address_space(1))) void*)(gB + k0),
            (__attribute__((address_space(3))) void*)dB, 16, 0, 0);
        __builtin_amdgcn_global_load_lds(
            (const __attribute__((address_space(1))) void*)(gB + 16 * (long)GK + k0),
            (__attribute__((address_space(3))) void*)(dB + 16 * 32), 16, 0, 0);
    };

    stage(0, 0);
    int pb = 0;
    for (int k0 = 0; k0 < GK; k0 += 32) {
        __syncthreads();                 // drains vmcnt: buf[pb] ready; lgkm: prev reads of buf[pb^1] done
        if (k0 + 32 < GK) stage(k0 + 32, pb ^ 1);   // head start = full compute phase

        const _Float16* cA = sA[pb];
        const _Float16* cB = sB[pb];
        v8h af[4], bf[4];
        #pragma unroll
        for (int i = 0; i < 4; ++i) {
            af[i] = *(const v8h*)&cA[aoff[i]];
            bf[i] = *(const v8h*)&cB[boff[i]];
        }
        #pragma unroll
        for (int i = 0; i < 4; ++i) {
            #pragma unroll
            for (int j = 0; j < 4; ++j)
                acc[i][j] = __builtin_amdgcn_mfma_f32_16x16x32_f16(af[i], bf[j], acc[i][j], 0, 0, 0);
        }
        pb ^= 1;
    }

    // epilogue: C/D layout col=lane&15, row=(lane>>4)*4+reg (m89-verified)
    #pragma unroll
    for (int j = 0; j < 4; ++j) {
        const long col = tile_n + (wn << 6) + (j << 4) + fr;
        if (col < GN) {
            const float bv = bias[col];
            #pragma unroll
            for (int i = 0; i < 4; ++i) {
                const long row = tile_m + (wm << 6) + (i << 4) + ((lane >> 4) << 2);
                #pragma unroll
                for (int r = 0; r < 4; ++r) {
                    float v = acc[i][j][r] + bv;
                    v = v > 0.f ? v : 0.f;
                    C[(row + r) * (long)GN + col] = (_Float16)v;
                }
            }
        }
    }
}

// ---------------------------------------------------------------------------
// Final projection: out[b,o] = sum_k F[b,k]*wo[o,k] + bo[o].
// 4 waves per row (256 threads!), vectorized, LDS cross-wave reduce.
// ---------------------------------------------------------------------------
__global__ __launch_bounds__(256) void final_out(
    const _Float16* __restrict__ F, const float* __restrict__ wo,
    const float* __restrict__ bo, float* __restrict__ out)
{
    __shared__ float red[4][8];
    const long b   = blockIdx.x;
    const int tid  = threadIdx.x;
    const int lane = tid & 63;
    const int wave = tid >> 6;
    float acc[5] = {0.f, 0.f, 0.f, 0.f, 0.f};
    const _Float16* f = F + b * GK;

    // 1608 chunks of 4 fp16; wave w handles chunks [w*402, (w+1)*402)
    const int c1 = (wave + 1) * 402;
    for (int c = wave * 402 + lane; c < c1; c += 64) {
        const int k = c << 2;
        v4h f4 = *(const v4h*)(f + k);
        const float f0 = (float)f4[0], f1 = (float)f4[1];
        const float f2 = (float)f4[2], f3 = (float)f4[3];
        #pragma unroll
        for (int o = 0; o < 5; ++o) {
            const float4 w4 = *(const float4*)(wo + o * GK + k);
            acc[o] += f0 * w4.x + f1 * w4.y + f2 * w4.z + f3 * w4.w;
        }
    }
    #pragma unroll
    for (int o = 0; o < 5; ++o) {
        #pragma unroll
        for (int off = 32; off > 0; off >>= 1) acc[o] += __shfl_down(acc[o], off, 64);
    }
    if (lane == 0) {
        #pragma unroll
        for (int o = 0; o < 5; ++o) red[wave][o] = acc[o];
    }
    __syncthreads();
    if (tid < 5)
        out[b * 5 + tid] = red[0][tid] + red[1][tid] + red[2][tid] + red[3][tid] + bo[tid];
}

// ---------------------------------------------------------------------------
extern "C" void kernel_launch(void* const* d_in, const int* in_sizes, int n_in,
                              void* d_out, int out_size, void* d_ws, size_t ws_size,
                              hipStream_t stream)
{
    const float* x  = (const float*)d_in[0];
    const float* w1 = (const float*)d_in[1];
    const float* b1 = (const float*)d_in[2];
    const float* w2 = (const float*)d_in[3];
    const float* b2 = (const float*)d_in[4];
    const float* wl = (const float*)d_in[5];
    const float* bl = (const float*)d_in[6];
    const float* wo = (const float*)d_in[7];
    const float* bo = (const float*)d_in[8];
    float* out = (float*)d_out;

    char* ws = (char*)d_ws;
    _Float16* Wh = (_Float16*)ws;                                   // 6528*6432*2 = 83,976,192 B
    _Float16* F0 = (_Float16*)(ws + 83976192);                      // 2048*6432*2 = 26,345,472 B
    _Float16* F1 = (_Float16*)(ws + 83976192 + 26345472);

    convert_w<<<dim3(7, GNPAD), 256, 0, stream>>>(wl, Wh);
    conv_feat<<<GM, 256, 0, stream>>>(x, w1, b1, w2, b2, F0);
    gemm_relu<<<816, 256, 0, stream>>>(F0, Wh, bl, F1);
    gemm_relu<<<816, 256, 0, stream>>>(F1, Wh, bl, F0);
    gemm_relu<<<816, 256, 0, stream>>>(F0, Wh, bl, F1);
    gemm_relu<<<816, 256, 0, stream>>>(F1, Wh, bl, F0);
    final_out<<<GM, 256, 0, stream>>>(F0, wo, bo, out);
}

// Round 4
// 1579.269 us; speedup vs baseline: 1.1590x; 1.0928x over previous
//
#include <hip/hip_runtime.h>

typedef _Float16 v8h __attribute__((ext_vector_type(8)));
typedef _Float16 v4h __attribute__((ext_vector_type(4)));
typedef float    v4f __attribute__((ext_vector_type(4)));

#define GK 6432      // K of the big GEMM (= flatten size F)
#define GN 6432      // N of the big GEMM
#define GM 2048      // batch
#define GNPAD 6528   // N padded to 51*128 for safe staging

// ---------------------------------------------------------------------------
// Weight conversion: wl fp32 [6432,6432] -> fp16 [6528,6432], pad rows zeroed
// ---------------------------------------------------------------------------
__global__ void convert_w(const float* __restrict__ wl, _Float16* __restrict__ Wh)
{
    const int row = blockIdx.y;
    const int col = (blockIdx.x * 256 + threadIdx.x) * 4;
    if (col >= GK) return;
    v4h h;
    if (row < GN) {
        const float4 f = *(const float4*)(wl + (long)row * GK + col);
        h[0] = (_Float16)f.x; h[1] = (_Float16)f.y;
        h[2] = (_Float16)f.z; h[3] = (_Float16)f.w;
    } else {
        h[0] = (_Float16)0.f; h[1] = (_Float16)0.f;
        h[2] = (_Float16)0.f; h[3] = (_Float16)0.f;
    }
    *(v4h*)(Wh + (long)row * GK + col) = h;
}

// ---------------------------------------------------------------------------
// Multi-scale conv feature extractor. One block per batch item.
// Produces F0 [2048, 6432] fp16, layout b*6432 + c2*201 + v.
// ---------------------------------------------------------------------------
#define SX   0
#define SX2  2048
#define SX4  3136
#define SW1  3712
#define SB1  4032
#define SW2  4048
#define SB2  6608
#define SP1  6640
#define LDSZ 13808

__global__ __launch_bounds__(256) void conv_feat(
    const float* __restrict__ x,
    const float* __restrict__ w1, const float* __restrict__ b1,
    const float* __restrict__ w2, const float* __restrict__ b2,
    _Float16* __restrict__ F0)
{
    __shared__ float lds[LDSZ];
    const int tid = threadIdx.x;
    const long b  = blockIdx.x;

    for (int i = tid; i < 1920; i += 256) {
        int c = i / 480, t = i % 480;
        lds[SX + c * 512 + t] = x[(b * 4 + c) * 480 + t];
    }
    for (int i = tid; i < 320;  i += 256) lds[SW1 + i] = w1[i];
    for (int i = tid; i < 16;   i += 256) lds[SB1 + i] = b1[i];
    for (int i = tid; i < 2560; i += 256) lds[SW2 + i] = w2[i];
    for (int i = tid; i < 32;   i += 256) lds[SB2 + i] = b2[i];
    __syncthreads();

    for (int i = tid; i < 960; i += 256) {
        int c = i / 240, t = i % 240;
        lds[SX2 + c * 272 + t] = 0.5f * (lds[SX + c * 512 + 2 * t] + lds[SX + c * 512 + 2 * t + 1]);
    }
    for (int i = tid; i < 480; i += 256) {
        int c = i / 120, t = i % 120;
        float s = lds[SX + c * 512 + 4 * t]     + lds[SX + c * 512 + 4 * t + 1]
                + lds[SX + c * 512 + 4 * t + 2] + lds[SX + c * 512 + 4 * t + 3];
        lds[SX4 + c * 144 + t] = 0.25f * s;
    }
    __syncthreads();

    for (int jid = tid; jid < 16 * 34; jid += 256) {
        const int c1 = jid / 34, rid = jid % 34;
        const int sidx = (rid < 19) ? 0 : (rid < 29 ? 1 : 2);
        const int r0   = (sidx == 0) ? rid : (sidx == 1 ? rid - 19 : rid - 29);
        const int u0   = r0 * 13;
        const int xbase  = (sidx == 0) ? SX  : (sidx == 1 ? SX2 : SX4);
        const int xpitch = (sidx == 0) ? 512 : (sidx == 1 ? 272 : 144);
        const int P      = (sidx == 0) ? 238 : (sidx == 1 ? 118 : 58);
        const int pofs   = (sidx == 0) ? 0   : (sidx == 1 ? 238 : 356);

        float acc[26];
        const float bias = lds[SB1 + c1];
        #pragma unroll
        for (int i = 0; i < 26; ++i) acc[i] = bias;

        #pragma unroll
        for (int ci = 0; ci < 4; ++ci) {
            float w[30];
            const float* xr = &lds[xbase + ci * xpitch + 2 * u0];
            #pragma unroll
            for (int q = 0; q < 15; ++q) {
                float2 t2 = *(const float2*)(xr + 2 * q);
                w[2 * q] = t2.x; w[2 * q + 1] = t2.y;
            }
            float wt[5];
            #pragma unroll
            for (int k = 0; k < 5; ++k) wt[k] = lds[SW1 + (c1 * 4 + ci) * 5 + k];
            #pragma unroll
            for (int i = 0; i < 26; ++i) {
                #pragma unroll
                for (int k = 0; k < 5; ++k) acc[i] += w[i + k] * wt[k];
            }
        }
        #pragma unroll
        for (int i = 0; i < 13; ++i) {
            int u = u0 + i;
            if (u < P)
                lds[SP1 + c1 * 448 + pofs + u] = fmaxf(fmaxf(acc[2 * i], acc[2 * i + 1]), 0.f);
        }
    }
    __syncthreads();

    for (int jid = tid; jid < 32 * 17; jid += 256) {
        const int c2 = jid / 17, rid = jid % 17;
        const int sidx = (rid < 9) ? 0 : (rid < 14 ? 1 : 2);
        const int r0   = (sidx == 0) ? rid : (sidx == 1 ? rid - 9 : rid - 14);
        const int v0   = r0 * 13;
        const int pbase = (sidx == 0) ? 0   : (sidx == 1 ? 238 : 356);
        const int Pv    = (sidx == 0) ? 117 : (sidx == 1 ? 57  : 27);
        const int vout  = (sidx == 0) ? 0   : (sidx == 1 ? 117 : 174);

        float acc[26];
        const float bias = lds[SB2 + c2];
        #pragma unroll
        for (int i = 0; i < 26; ++i) acc[i] = bias;

        for (int c1 = 0; c1 < 16; ++c1) {
            float w[30];
            const float* pr = &lds[SP1 + c1 * 448 + pbase + 2 * v0];
            #pragma unroll
            for (int q = 0; q < 15; ++q) {
                float2 t2 = *(const float2*)(pr + 2 * q);
                w[2 * q] = t2.x; w[2 * q + 1] = t2.y;
            }
            float wt[5];
            #pragma unroll
            for (int k = 0; k < 5; ++k) wt[k] = lds[SW2 + (c2 * 16 + c1) * 5 + k];
            #pragma unroll
            for (int i = 0; i < 26; ++i) {
                #pragma unroll
                for (int k = 0; k < 5; ++k) acc[i] += w[i + k] * wt[k];
            }
        }
        #pragma unroll
        for (int i = 0; i < 13; ++i) {
            int v = v0 + i;
            if (v < Pv) {
                float f = fmaxf(fmaxf(acc[2 * i], acc[2 * i + 1]), 0.f);
                F0[b * GK + c2 * 201 + vout + v] = (_Float16)f;
            }
        }
    }
}

// ---------------------------------------------------------------------------
// NT GEMM: C = relu(A @ Bw^T + bias). BM=64, BN=128, BK=32 tiles ->
// 32x51 = 1632 blocks (6.4/CU, 25.5 waves/CU for latency hiding).
// Double-buffered LDS (24 KB), XOR-swizzled layout, XCD n-affinity swizzle.
// 4 waves in 2x2; each wave: 2x4 frags of 16x16x32 fp16 MFMA, fp32 accum.
// ---------------------------------------------------------------------------
__global__ __launch_bounds__(256) void gemm_relu(
    const _Float16* __restrict__ A, const _Float16* __restrict__ Bw,
    const float* __restrict__ bias, _Float16* __restrict__ C)
{
    __shared__ _Float16 sA[2][64 * 32];
    __shared__ _Float16 sB[2][128 * 32];
    const int tid  = threadIdx.x;
    const int lane = tid & 63;
    const int wave = tid >> 6;
    const int wm = wave & 1, wn = wave >> 1;

    // XCD swizzle: in a group of 256 ids, XCD (id&7) sees one n-tile and all
    // 32 m-tiles -> its 1.6MB B-strip stays L2-resident.
    const int id = blockIdx.x;          // 0..1631
    int n_t, m_t;
    if (id < 1536) {
        n_t = ((id >> 8) << 3) | (id & 7);
        m_t = (id >> 3) & 31;
    } else {
        const int r = id - 1536;
        n_t = 48 + r % 3;
        m_t = r / 3;
    }
    const long tile_m = (long)m_t * 64;
    const long tile_n = (long)n_t * 128;

    // staging: lane l covers LDS chunk (row = base + l/4, slot = l&3).
    // XOR swizzle: slot q at row r holds global k-phase q ^ s(r),
    // s(r) = (r&3) ^ ((r>>2)&3)  (function of r mod 16 only).
    const int lr   = lane >> 2;
    const int sfn  = (lr & 3) ^ ((lr >> 2) & 3);
    const int scol = (((lane & 3) ^ sfn) << 3);       // fp16 elems
    const _Float16* gA = A  + (tile_m + (wave << 4) + lr) * (long)GK + scol;   // 16 rows/wave
    const _Float16* gB = Bw + (tile_n + (wave << 5) + lr) * (long)GK + scol;   // 32 rows/wave

    // fragment read offsets (swizzled slot)
    const int fr = lane & 15;
    const int fp = lane >> 4;                          // k-phase 0..3
    const int fslot = fp ^ ((fr & 3) ^ ((fr >> 2) & 3));
    int aoff[2], boff[4];
    #pragma unroll
    for (int i = 0; i < 2; ++i)
        aoff[i] = ((wm << 5) + (i << 4) + fr) * 32 + (fslot << 3);
    #pragma unroll
    for (int j = 0; j < 4; ++j)
        boff[j] = ((wn << 6) + (j << 4) + fr) * 32 + (fslot << 3);

    v4f acc[2][4];
    #pragma unroll
    for (int i = 0; i < 2; ++i) {
        #pragma unroll
        for (int j = 0; j < 4; ++j) { v4f z = {0.f, 0.f, 0.f, 0.f}; acc[i][j] = z; }
    }

    auto stage = [&](int k0, int buf) {
        _Float16* dA = &sA[buf][(wave << 4) * 32];
        _Float16* dB = &sB[buf][(wave << 5) * 32];
        __builtin_amdgcn_global_load_lds(
            (const __attribute__((address_space(1))) void*)(gA + k0),
            (__attribute__((address_space(3))) void*)dA, 16, 0, 0);
        __builtin_amdgcn_global_load_lds(
            (const __attribute__((address_space(1))) void*)(gB + k0),
            (__attribute__((address_space(3))) void*)dB, 16, 0, 0);
        __builtin_amdgcn_global_load_lds(
            (const __attribute__((address_space(1))) void*)(gB + 16 * (long)GK + k0),
            (__attribute__((address_space(3))) void*)(dB + 16 * 32), 16, 0, 0);
    };

    stage(0, 0);
    int pb = 0;
    for (int k0 = 0; k0 < GK; k0 += 32) {
        __syncthreads();                 // buf[pb] ready; prev reads of buf[pb^1] done
        if (k0 + 32 < GK) stage(k0 + 32, pb ^ 1);   // full compute phase of head start

        const _Float16* cA = sA[pb];
        const _Float16* cB = sB[pb];
        v8h af[2], bf[4];
        #pragma unroll
        for (int i = 0; i < 2; ++i) af[i] = *(const v8h*)&cA[aoff[i]];
        #pragma unroll
        for (int j = 0; j < 4; ++j) bf[j] = *(const v8h*)&cB[boff[j]];
        #pragma unroll
        for (int i = 0; i < 2; ++i) {
            #pragma unroll
            for (int j = 0; j < 4; ++j)
                acc[i][j] = __builtin_amdgcn_mfma_f32_16x16x32_f16(af[i], bf[j], acc[i][j], 0, 0, 0);
        }
        pb ^= 1;
    }

    // epilogue: C/D layout col=lane&15, row=(lane>>4)*4+reg (m89-verified)
    #pragma unroll
    for (int j = 0; j < 4; ++j) {
        const long col = tile_n + (wn << 6) + (j << 4) + fr;
        if (col < GN) {
            const float bv = bias[col];
            #pragma unroll
            for (int i = 0; i < 2; ++i) {
                const long row = tile_m + (wm << 5) + (i << 4) + ((lane >> 4) << 2);
                #pragma unroll
                for (int r = 0; r < 4; ++r) {
                    float v = acc[i][j][r] + bv;
                    v = v > 0.f ? v : 0.f;
                    C[(row + r) * (long)GN + col] = (_Float16)v;
                }
            }
        }
    }
}

// ---------------------------------------------------------------------------
// Final projection: out[b,o] = sum_k F[b,k]*wo[o,k] + bo[o].
// 4 waves per row (256 threads), vectorized, LDS cross-wave reduce.
// ---------------------------------------------------------------------------
__global__ __launch_bounds__(256) void final_out(
    const _Float16* __restrict__ F, const float* __restrict__ wo,
    const float* __restrict__ bo, float* __restrict__ out)
{
    __shared__ float red[4][8];
    const long b   = blockIdx.x;
    const int tid  = threadIdx.x;
    const int lane = tid & 63;
    const int wave = tid >> 6;
    float acc[5] = {0.f, 0.f, 0.f, 0.f, 0.f};
    const _Float16* f = F + b * GK;

    const int c1 = (wave + 1) * 402;
    for (int c = wave * 402 + lane; c < c1; c += 64) {
        const int k = c << 2;
        v4h f4 = *(const v4h*)(f + k);
        const float f0 = (float)f4[0], f1 = (float)f4[1];
        const float f2 = (float)f4[2], f3 = (float)f4[3];
        #pragma unroll
        for (int o = 0; o < 5; ++o) {
            const float4 w4 = *(const float4*)(wo + o * GK + k);
            acc[o] += f0 * w4.x + f1 * w4.y + f2 * w4.z + f3 * w4.w;
        }
    }
    #pragma unroll
    for (int o = 0; o < 5; ++o) {
        #pragma unroll
        for (int off = 32; off > 0; off >>= 1) acc[o] += __shfl_down(acc[o], off, 64);
    }
    if (lane == 0) {
        #pragma unroll
        for (int o = 0; o < 5; ++o) red[wave][o] = acc[o];
    }
    __syncthreads();
    if (tid < 5)
        out[b * 5 + tid] = red[0][tid] + red[1][tid] + red[2][tid] + red[3][tid] + bo[tid];
}

// ---------------------------------------------------------------------------
extern "C" void kernel_launch(void* const* d_in, const int* in_sizes, int n_in,
                              void* d_out, int out_size, void* d_ws, size_t ws_size,
                              hipStream_t stream)
{
    const float* x  = (const float*)d_in[0];
    const float* w1 = (const float*)d_in[1];
    const float* b1 = (const float*)d_in[2];
    const float* w2 = (const float*)d_in[3];
    const float* b2 = (const float*)d_in[4];
    const float* wl = (const float*)d_in[5];
    const float* bl = (const float*)d_in[6];
    const float* wo = (const float*)d_in[7];
    const float* bo = (const float*)d_in[8];
    float* out = (float*)d_out;

    char* ws = (char*)d_ws;
    _Float16* Wh = (_Float16*)ws;                                   // 6528*6432*2 = 83,976,192 B
    _Float16* F0 = (_Float16*)(ws + 83976192);                      // 2048*6432*2 = 26,345,472 B
    _Float16* F1 = (_Float16*)(ws + 83976192 + 26345472);

    convert_w<<<dim3(7, GNPAD), 256, 0, stream>>>(wl, Wh);
    conv_feat<<<GM, 256, 0, stream>>>(x, w1, b1, w2, b2, F0);
    gemm_relu<<<1632, 256, 0, stream>>>(F0, Wh, bl, F1);
    gemm_relu<<<1632, 256, 0, stream>>>(F1, Wh, bl, F0);
    gemm_relu<<<1632, 256, 0, stream>>>(F0, Wh, bl, F1);
    gemm_relu<<<1632, 256, 0, stream>>>(F1, Wh, bl, F0);
    final_out<<<GM, 256, 0, stream>>>(F0, wo, bo, out);
}

// Round 5
// 1347.864 us; speedup vs baseline: 1.3580x; 1.1717x over previous
//
#include <hip/hip_runtime.h>

typedef _Float16 v8h __attribute__((ext_vector_type(8)));
typedef _Float16 v4h __attribute__((ext_vector_type(4)));
typedef float    v4f __attribute__((ext_vector_type(4)));

#define GK 6432      // K of the big GEMM (= flatten size F)
#define GN 6432      // N of the big GEMM
#define GM 2048      // batch
#define GNPAD 6528   // N padded to 51*128 for safe staging

// ---------------------------------------------------------------------------
// Weight conversion: wl fp32 [6432,6432] -> fp16 [6528,6432], pad rows zeroed
// ---------------------------------------------------------------------------
__global__ void convert_w(const float* __restrict__ wl, _Float16* __restrict__ Wh)
{
    const int row = blockIdx.y;
    const int col = (blockIdx.x * 256 + threadIdx.x) * 4;
    if (col >= GK) return;
    v4h h;
    if (row < GN) {
        const float4 f = *(const float4*)(wl + (long)row * GK + col);
        h[0] = (_Float16)f.x; h[1] = (_Float16)f.y;
        h[2] = (_Float16)f.z; h[3] = (_Float16)f.w;
    } else {
        h[0] = (_Float16)0.f; h[1] = (_Float16)0.f;
        h[2] = (_Float16)0.f; h[3] = (_Float16)0.f;
    }
    *(v4h*)(Wh + (long)row * GK + col) = h;
}

// ---------------------------------------------------------------------------
// Multi-scale conv feature extractor. One block per batch item.
// Produces F0 [2048, 6432] fp16, layout b*6432 + c2*201 + v.
// ---------------------------------------------------------------------------
#define SX   0
#define SX2  2048
#define SX4  3136
#define SW1  3712
#define SB1  4032
#define SW2  4048
#define SB2  6608
#define SP1  6640
#define LDSZ 13808

__global__ __launch_bounds__(256) void conv_feat(
    const float* __restrict__ x,
    const float* __restrict__ w1, const float* __restrict__ b1,
    const float* __restrict__ w2, const float* __restrict__ b2,
    _Float16* __restrict__ F0)
{
    __shared__ float lds[LDSZ];
    const int tid = threadIdx.x;
    const long b  = blockIdx.x;

    for (int i = tid; i < 1920; i += 256) {
        int c = i / 480, t = i % 480;
        lds[SX + c * 512 + t] = x[(b * 4 + c) * 480 + t];
    }
    for (int i = tid; i < 320;  i += 256) lds[SW1 + i] = w1[i];
    for (int i = tid; i < 16;   i += 256) lds[SB1 + i] = b1[i];
    for (int i = tid; i < 2560; i += 256) lds[SW2 + i] = w2[i];
    for (int i = tid; i < 32;   i += 256) lds[SB2 + i] = b2[i];
    __syncthreads();

    for (int i = tid; i < 960; i += 256) {
        int c = i / 240, t = i % 240;
        lds[SX2 + c * 272 + t] = 0.5f * (lds[SX + c * 512 + 2 * t] + lds[SX + c * 512 + 2 * t + 1]);
    }
    for (int i = tid; i < 480; i += 256) {
        int c = i / 120, t = i % 120;
        float s = lds[SX + c * 512 + 4 * t]     + lds[SX + c * 512 + 4 * t + 1]
                + lds[SX + c * 512 + 4 * t + 2] + lds[SX + c * 512 + 4 * t + 3];
        lds[SX4 + c * 144 + t] = 0.25f * s;
    }
    __syncthreads();

    for (int jid = tid; jid < 16 * 34; jid += 256) {
        const int c1 = jid / 34, rid = jid % 34;
        const int sidx = (rid < 19) ? 0 : (rid < 29 ? 1 : 2);
        const int r0   = (sidx == 0) ? rid : (sidx == 1 ? rid - 19 : rid - 29);
        const int u0   = r0 * 13;
        const int xbase  = (sidx == 0) ? SX  : (sidx == 1 ? SX2 : SX4);
        const int xpitch = (sidx == 0) ? 512 : (sidx == 1 ? 272 : 144);
        const int P      = (sidx == 0) ? 238 : (sidx == 1 ? 118 : 58);
        const int pofs   = (sidx == 0) ? 0   : (sidx == 1 ? 238 : 356);

        float acc[26];
        const float bias = lds[SB1 + c1];
        #pragma unroll
        for (int i = 0; i < 26; ++i) acc[i] = bias;

        #pragma unroll
        for (int ci = 0; ci < 4; ++ci) {
            float w[30];
            const float* xr = &lds[xbase + ci * xpitch + 2 * u0];
            #pragma unroll
            for (int q = 0; q < 15; ++q) {
                float2 t2 = *(const float2*)(xr + 2 * q);
                w[2 * q] = t2.x; w[2 * q + 1] = t2.y;
            }
            float wt[5];
            #pragma unroll
            for (int k = 0; k < 5; ++k) wt[k] = lds[SW1 + (c1 * 4 + ci) * 5 + k];
            #pragma unroll
            for (int i = 0; i < 26; ++i) {
                #pragma unroll
                for (int k = 0; k < 5; ++k) acc[i] += w[i + k] * wt[k];
            }
        }
        #pragma unroll
        for (int i = 0; i < 13; ++i) {
            int u = u0 + i;
            if (u < P)
                lds[SP1 + c1 * 448 + pofs + u] = fmaxf(fmaxf(acc[2 * i], acc[2 * i + 1]), 0.f);
        }
    }
    __syncthreads();

    for (int jid = tid; jid < 32 * 17; jid += 256) {
        const int c2 = jid / 17, rid = jid % 17;
        const int sidx = (rid < 9) ? 0 : (rid < 14 ? 1 : 2);
        const int r0   = (sidx == 0) ? rid : (sidx == 1 ? rid - 9 : rid - 14);
        const int v0   = r0 * 13;
        const int pbase = (sidx == 0) ? 0   : (sidx == 1 ? 238 : 356);
        const int Pv    = (sidx == 0) ? 117 : (sidx == 1 ? 57  : 27);
        const int vout  = (sidx == 0) ? 0   : (sidx == 1 ? 117 : 174);

        float acc[26];
        const float bias = lds[SB2 + c2];
        #pragma unroll
        for (int i = 0; i < 26; ++i) acc[i] = bias;

        for (int c1 = 0; c1 < 16; ++c1) {
            float w[30];
            const float* pr = &lds[SP1 + c1 * 448 + pbase + 2 * v0];
            #pragma unroll
            for (int q = 0; q < 15; ++q) {
                float2 t2 = *(const float2*)(pr + 2 * q);
                w[2 * q] = t2.x; w[2 * q + 1] = t2.y;
            }
            float wt[5];
            #pragma unroll
            for (int k = 0; k < 5; ++k) wt[k] = lds[SW2 + (c2 * 16 + c1) * 5 + k];
            #pragma unroll
            for (int i = 0; i < 26; ++i) {
                #pragma unroll
                for (int k = 0; k < 5; ++k) acc[i] += w[i + k] * wt[k];
            }
        }
        #pragma unroll
        for (int i = 0; i < 13; ++i) {
            int v = v0 + i;
            if (v < Pv) {
                float f = fmaxf(fmaxf(acc[2 * i], acc[2 * i + 1]), 0.f);
                F0[b * GK + c2 * 201 + vout + v] = (_Float16)f;
            }
        }
    }
}

// ---------------------------------------------------------------------------
// NT GEMM: C = relu(A @ Bw^T + bias). Block tile 128x128, BK=32, 2 waves.
// Wave tile 128m x 64n (8x4 frags of 16x16x32 fp16 MFMA, fp32 accum):
// FLOP per LDS-read-byte = 42.7 (vs 32 @R3, 21.3 @R4) -- LDS-pipe relief.
// Wave 0 stages A-tile, wave 1 stages B-tile (8x global_load_lds w16 each).
// Double-buffered LDS (32 KB), XOR-swizzled layout, XCD n-affinity swizzle.
// ---------------------------------------------------------------------------
__global__ __launch_bounds__(128, 2) void gemm_relu(
    const _Float16* __restrict__ A, const _Float16* __restrict__ Bw,
    const float* __restrict__ bias, _Float16* __restrict__ C)
{
    __shared__ _Float16 sA[2][128 * 32];
    __shared__ _Float16 sB[2][128 * 32];
    const int tid  = threadIdx.x;
    const int lane = tid & 63;
    const int wave = tid >> 6;          // 0: stages A, frags n-half 0; 1: stages B, n-half 1

    // XCD swizzle: in a group of 128 ids, XCD (id&7) sees one n-tile and all
    // 16 m-tiles -> its 1.6MB B-strip stays L2-resident.
    const int id = blockIdx.x;          // 0..815
    int n_t, m_t;
    if (id < 768) {
        n_t = ((id >> 7) << 3) | (id & 7);
        m_t = (id >> 3) & 15;
    } else {
        const int r = id - 768;
        n_t = 48 + r % 3;
        m_t = r / 3;
    }
    const long tile_m = (long)m_t * 128;
    const long tile_n = (long)n_t * 128;

    // staging: each wave stages one 128x32 tile with 8 insts; inst t covers
    // rows 16t..16t+15. lane l: row-in-16 = l>>2, k-slot = l&3 (XOR-swizzled).
    // XOR swizzle: slot q at row r holds global k-phase q ^ s(r),
    // s(r) = (r&3) ^ ((r>>2)&3)   (function of r mod 16).
    const int lr   = lane >> 2;
    const int sfn  = (lr & 3) ^ ((lr >> 2) & 3);
    const int scol = (((lane & 3) ^ sfn) << 3);       // fp16 elems
    const _Float16* gS = (wave == 0)
        ? A  + (tile_m + lr) * (long)GK + scol
        : Bw + (tile_n + lr) * (long)GK + scol;

    // fragment read offsets (swizzled slot)
    const int fr = lane & 15;
    const int fp = lane >> 4;                          // k-phase 0..3
    const int fslot = fp ^ ((fr & 3) ^ ((fr >> 2) & 3));
    int aoff[8], boff[4];
    #pragma unroll
    for (int i = 0; i < 8; ++i)
        aoff[i] = ((i << 4) + fr) * 32 + (fslot << 3);
    #pragma unroll
    for (int j = 0; j < 4; ++j)
        boff[j] = ((wave << 6) + (j << 4) + fr) * 32 + (fslot << 3);

    v4f acc[8][4];
    #pragma unroll
    for (int i = 0; i < 8; ++i) {
        #pragma unroll
        for (int j = 0; j < 4; ++j) { v4f z = {0.f, 0.f, 0.f, 0.f}; acc[i][j] = z; }
    }

    auto stage = [&](int k0, int buf) {
        _Float16* dst = (wave == 0) ? sA[buf] : sB[buf];
        #pragma unroll
        for (int t = 0; t < 8; ++t) {
            __builtin_amdgcn_global_load_lds(
                (const __attribute__((address_space(1))) void*)(gS + (t * 16) * (long)GK + k0),
                (__attribute__((address_space(3))) void*)(dst + t * 16 * 32), 16, 0, 0);
        }
    };

    stage(0, 0);
    int pb = 0;
    for (int k0 = 0; k0 < GK; k0 += 32) {
        __syncthreads();                 // buf[pb] staged; prev reads of buf[pb^1] done
        if (k0 + 32 < GK) stage(k0 + 32, pb ^ 1);   // full compute phase of head start

        const _Float16* cA = sA[pb];
        const _Float16* cB = sB[pb];
        v8h af[8], bf[4];
        #pragma unroll
        for (int j = 0; j < 4; ++j) bf[j] = *(const v8h*)&cB[boff[j]];
        #pragma unroll
        for (int i = 0; i < 8; ++i) af[i] = *(const v8h*)&cA[aoff[i]];
        #pragma unroll
        for (int i = 0; i < 8; ++i) {
            #pragma unroll
            for (int j = 0; j < 4; ++j)
                acc[i][j] = __builtin_amdgcn_mfma_f32_16x16x32_f16(af[i], bf[j], acc[i][j], 0, 0, 0);
        }
        pb ^= 1;
    }

    // epilogue: C/D layout col=lane&15, row=(lane>>4)*4+reg (m89-verified)
    #pragma unroll
    for (int j = 0; j < 4; ++j) {
        const long col = tile_n + (wave << 6) + (j << 4) + fr;
        if (col < GN) {
            const float bv = bias[col];
            #pragma unroll
            for (int i = 0; i < 8; ++i) {
                const long row = tile_m + (i << 4) + (fp << 2);
                #pragma unroll
                for (int r = 0; r < 4; ++r) {
                    float v = acc[i][j][r] + bv;
                    v = v > 0.f ? v : 0.f;
                    C[(row + r) * (long)GN + col] = (_Float16)v;
                }
            }
        }
    }
}

// ---------------------------------------------------------------------------
// Final projection: out[b,o] = sum_k F[b,k]*wo[o,k] + bo[o].
// 4 waves per row (256 threads), vectorized, LDS cross-wave reduce.
// ---------------------------------------------------------------------------
__global__ __launch_bounds__(256) void final_out(
    const _Float16* __restrict__ F, const float* __restrict__ wo,
    const float* __restrict__ bo, float* __restrict__ out)
{
    __shared__ float red[4][8];
    const long b   = blockIdx.x;
    const int tid  = threadIdx.x;
    const int lane = tid & 63;
    const int wave = tid >> 6;
    float acc[5] = {0.f, 0.f, 0.f, 0.f, 0.f};
    const _Float16* f = F + b * GK;

    const int c1 = (wave + 1) * 402;
    for (int c = wave * 402 + lane; c < c1; c += 64) {
        const int k = c << 2;
        v4h f4 = *(const v4h*)(f + k);
        const float f0 = (float)f4[0], f1 = (float)f4[1];
        const float f2 = (float)f4[2], f3 = (float)f4[3];
        #pragma unroll
        for (int o = 0; o < 5; ++o) {
            const float4 w4 = *(const float4*)(wo + o * GK + k);
            acc[o] += f0 * w4.x + f1 * w4.y + f2 * w4.z + f3 * w4.w;
        }
    }
    #pragma unroll
    for (int o = 0; o < 5; ++o) {
        #pragma unroll
        for (int off = 32; off > 0; off >>= 1) acc[o] += __shfl_down(acc[o], off, 64);
    }
    if (lane == 0) {
        #pragma unroll
        for (int o = 0; o < 5; ++o) red[wave][o] = acc[o];
    }
    __syncthreads();
    if (tid < 5)
        out[b * 5 + tid] = red[0][tid] + red[1][tid] + red[2][tid] + red[3][tid] + bo[tid];
}

// ---------------------------------------------------------------------------
extern "C" void kernel_launch(void* const* d_in, const int* in_sizes, int n_in,
                              void* d_out, int out_size, void* d_ws, size_t ws_size,
                              hipStream_t stream)
{
    const float* x  = (const float*)d_in[0];
    const float* w1 = (const float*)d_in[1];
    const float* b1 = (const float*)d_in[2];
    const float* w2 = (const float*)d_in[3];
    const float* b2 = (const float*)d_in[4];
    const float* wl = (const float*)d_in[5];
    const float* bl = (const float*)d_in[6];
    const float* wo = (const float*)d_in[7];
    const float* bo = (const float*)d_in[8];
    float* out = (float*)d_out;

    char* ws = (char*)d_ws;
    _Float16* Wh = (_Float16*)ws;                                   // 6528*6432*2 = 83,976,192 B
    _Float16* F0 = (_Float16*)(ws + 83976192);                      // 2048*6432*2 = 26,345,472 B
    _Float16* F1 = (_Float16*)(ws + 83976192 + 26345472);

    convert_w<<<dim3(7, GNPAD), 256, 0, stream>>>(wl, Wh);
    conv_feat<<<GM, 256, 0, stream>>>(x, w1, b1, w2, b2, F0);
    gemm_relu<<<816, 128, 0, stream>>>(F0, Wh, bl, F1);
    gemm_relu<<<816, 128, 0, stream>>>(F1, Wh, bl, F0);
    gemm_relu<<<816, 128, 0, stream>>>(F0, Wh, bl, F1);
    gemm_relu<<<816, 128, 0, stream>>>(F1, Wh, bl, F0);
    final_out<<<GM, 256, 0, stream>>>(F0, wo, bo, out);
}